// Round 1
// baseline (4534.180 us; speedup 1.0000x reference)
//
#include <hip/hip_runtime.h>
#include <math.h>

// ---- problem constants ----
constexpr int kV  = 16384;
constexpr int kD  = 768;
constexpr int kH  = 12;
constexpr int kDH = 64;
constexpr int kL  = 2;
constexpr int kF  = 3072;
constexpr int kC  = 64;     // chunk length
constexpr int kNR = 32;     // NB/2 rotations
constexpr int kNB = 64;     // number of buckets
constexpr int kB  = 2;
constexpr int kS  = 2048;
constexpr int kNC = kS / kC;  // 32 chunks

// ============================================================
// x = emb[ids] + pos_emb
// ============================================================
__global__ void embed_kernel(const int* __restrict__ ids, const float* __restrict__ emb,
                             const float* __restrict__ pos, float* __restrict__ x) {
    int row = blockIdx.x;            // b*S + s
    int s = row % kS;
    int id = ids[row];
    for (int d = threadIdx.x; d < kD; d += blockDim.x)
        x[(size_t)row * kD + d] = emb[(size_t)id * kD + d] + pos[(size_t)s * kD + d];
}

// ============================================================
// LayerNorm: y = (x-m)/sqrt(var+1e-12)*g + b   (row = 768)
// ============================================================
__global__ __launch_bounds__(256) void ln_kernel(const float* __restrict__ X,
                                                 const float* __restrict__ g,
                                                 const float* __restrict__ b,
                                                 float* __restrict__ Y) {
    int row = blockIdx.x;
    size_t base = (size_t)row * kD;
    int tid = threadIdx.x;
    float vals[3];
    float s = 0.f, s2 = 0.f;
    int i = 0;
    for (int d = tid; d < kD; d += 256, ++i) {
        float v = X[base + d];
        vals[i] = v; s += v; s2 += v * v;
    }
    for (int m = 32; m >= 1; m >>= 1) {
        s  += __shfl_xor(s,  m, 64);
        s2 += __shfl_xor(s2, m, 64);
    }
    __shared__ float red[2][4];
    int wid = tid >> 6, lane = tid & 63;
    if (lane == 0) { red[0][wid] = s; red[1][wid] = s2; }
    __syncthreads();
    float ts  = red[0][0] + red[0][1] + red[0][2] + red[0][3];
    float ts2 = red[1][0] + red[1][1] + red[1][2] + red[1][3];
    float mean = ts / kD;
    float var  = ts2 / kD - mean * mean;
    float rstd = 1.0f / sqrtf(var + 1e-12f);
    i = 0;
    for (int d = tid; d < kD; d += 256, ++i)
        Y[base + d] = (vals[i] - mean) * rstd * g[d] + b[d];
}

// ============================================================
// Generic SGEMM: C[M,N] = A[M,K] @ B[K,N] (+bias) (gelu?) (+residual)
// 64x64 tile / block(256), 4x4 micro-tile, K-step 16
// ============================================================
__global__ __launch_bounds__(256) void gemm_kernel(const float* __restrict__ A,
                                                   const float* __restrict__ Bm,
                                                   const float* __restrict__ bias,
                                                   const float* __restrict__ R,
                                                   float* __restrict__ Cm,
                                                   int M, int N, int K, int dogelu) {
    __shared__ float As[16][68];   // [kk][m], padded row -> 16B aligned
    __shared__ float Bs[16][68];   // [kk][n]
    int tid = threadIdx.x;
    int tx = tid & 15, ty = tid >> 4;
    int m0 = blockIdx.y << 6, n0 = blockIdx.x << 6;
    float acc[4][4] = {{0.f}};
    int aM = tid >> 2;             // (tid*4)/16
    int aK = (tid & 3) << 2;       // (tid*4)%16
    int bK = tid >> 4;             // (tid*4)/64
    int bN = (tid & 15) << 2;      // (tid*4)%64
    for (int k0 = 0; k0 < K; k0 += 16) {
        float4 a4 = *(const float4*)(A + (size_t)(m0 + aM) * K + k0 + aK);
        As[aK + 0][aM] = a4.x; As[aK + 1][aM] = a4.y;
        As[aK + 2][aM] = a4.z; As[aK + 3][aM] = a4.w;
        float4 b4 = *(const float4*)(Bm + (size_t)(k0 + bK) * N + n0 + bN);
        Bs[bK][bN + 0] = b4.x; Bs[bK][bN + 1] = b4.y;
        Bs[bK][bN + 2] = b4.z; Bs[bK][bN + 3] = b4.w;
        __syncthreads();
#pragma unroll
        for (int kk = 0; kk < 16; ++kk) {
            float a[4], bb[4];
#pragma unroll
            for (int i = 0; i < 4; ++i) a[i] = As[kk][ty * 4 + i];
#pragma unroll
            for (int j = 0; j < 4; ++j) bb[j] = Bs[kk][tx * 4 + j];
#pragma unroll
            for (int i = 0; i < 4; ++i)
#pragma unroll
                for (int j = 0; j < 4; ++j)
                    acc[i][j] += a[i] * bb[j];
        }
        __syncthreads();
    }
#pragma unroll
    for (int i = 0; i < 4; ++i) {
        int m = m0 + ty * 4 + i;
#pragma unroll
        for (int j = 0; j < 4; ++j) {
            int n = n0 + tx * 4 + j;
            float vv = acc[i][j];
            if (bias) vv += bias[n];
            if (dogelu) {
                float u = 0.7978845608028654f * (vv + 0.044715f * vv * vv * vv);
                vv = 0.5f * vv * (1.f + tanhf(u));
            }
            if (R) vv += R[(size_t)m * N + n];
            Cm[(size_t)m * N + n] = vv;
        }
    }
}

// ============================================================
// LSH bucketing: rotated = qk . rot ; bucket = argmax([r,-r])
// one thread per (b,h,s); double accumulation for tie robustness
// ============================================================
__global__ void bucket_kernel(const float* __restrict__ qk, const float* __restrict__ rot,
                              int* __restrict__ buckets) {
    int t = blockIdx.x * 256 + threadIdx.x;
    if (t >= kB * kH * kS) return;
    int b = t / (kH * kS);
    int h = (t / kS) % kH;
    int s = t % kS;
    const float* q  = qk + ((size_t)(b * kS + s)) * kD + h * kDH;
    const float* rr = rot + (size_t)h * kDH * kNR;
    float rv[kNR];
    for (int r = 0; r < kNR; ++r) {
        double acc = 0.0;
        for (int d = 0; d < kDH; ++d)
            acc += (double)q[d] * (double)rr[d * kNR + r];
        rv[r] = (float)acc;
    }
    float best = -INFINITY; int bi = 0;
    for (int idx = 0; idx < 2 * kNR; ++idx) {
        float v = (idx < kNR) ? rv[idx] : -rv[idx - kNR];
        if (v > best) { best = v; bi = idx; }   // first occurrence of max
    }
    buckets[t] = bi;
}

// ============================================================
// Stable counting sort of positions by bucket, per (b,h)
// order[rank] = s  (rank = ahead-in-smaller-buckets + earlier-equal)
// ============================================================
__global__ __launch_bounds__(256) void sort_kernel(const int* __restrict__ buckets,
                                                   int* __restrict__ order) {
    __shared__ int sb[kS];
    __shared__ int hist[kNB];
    __shared__ int offs[kNB];
    int bh = blockIdx.x;
    const int* bk = buckets + (size_t)bh * kS;
    for (int s = threadIdx.x; s < kS; s += 256) sb[s] = bk[s];
    for (int i = threadIdx.x; i < kNB; i += 256) hist[i] = 0;
    __syncthreads();
    for (int s = threadIdx.x; s < kS; s += 256) atomicAdd(&hist[sb[s]], 1);
    __syncthreads();
    if (threadIdx.x == 0) {
        int run = 0;
        for (int k = 0; k < kNB; ++k) { offs[k] = run; run += hist[k]; }
    }
    __syncthreads();
    for (int s = threadIdx.x; s < kS; s += 256) {
        int bkt = sb[s];
        int cnt = 0;
        for (int t = 0; t < s; ++t) cnt += (sb[t] == bkt) ? 1 : 0;
        order[(size_t)bh * kS + offs[bkt] + cnt] = s;
    }
}

// ============================================================
// Gather sorted qk/v, L2-normalize keys, gather buckets & mask.
// One wave (64 lanes) per sorted row.
// ============================================================
__global__ __launch_bounds__(256) void gather_kernel(const float* __restrict__ qk,
                                                     const float* __restrict__ v,
                                                     const int* __restrict__ buckets,
                                                     const int* __restrict__ amask,
                                                     const int* __restrict__ order,
                                                     float* __restrict__ sqk,
                                                     float* __restrict__ skey,
                                                     float* __restrict__ sv,
                                                     int* __restrict__ sb,
                                                     int* __restrict__ sm) {
    int wid = threadIdx.x >> 6, lane = threadIdx.x & 63;
    int i = blockIdx.x * 4 + wid;         // flat (b*H+h)*S + is
    int b  = i / (kH * kS);
    int h  = (i / kS) % kH;
    int j  = order[i];
    size_t src = ((size_t)(b * kS + j)) * kD + h * kDH + lane;
    float qv = qk[src];
    float vv = v[src];
    float ss = qv * qv;
    for (int m = 32; m >= 1; m >>= 1) ss += __shfl_xor(ss, m, 64);
    float nrm = sqrtf(ss) + 1e-6f;
    size_t o = (size_t)i * kDH + lane;
    sqk[o]  = qv;
    skey[o] = qv / nrm;
    sv[o]   = vv;
    if (lane == 0) {
        sb[i] = buckets[(size_t)(b * kH + h) * kS + j];
        sm[i] = amask[b * kS + j];
    }
}

// ============================================================
// Chunked LSH attention with 1-chunk lookback (wrapping).
// Block per (b,h,chunk). Output scattered to unsorted layout.
// ============================================================
__global__ __launch_bounds__(256) void attn_kernel(const float* __restrict__ sqk,
                                                   const float* __restrict__ skey,
                                                   const float* __restrict__ sv,
                                                   const int* __restrict__ sb,
                                                   const int* __restrict__ sm,
                                                   const int* __restrict__ order,
                                                   float* __restrict__ aout) {
    __shared__ float ke[2 * kC][kDH + 1];
    __shared__ float qc[kC][kDH];
    __shared__ int bc[kC], icc[kC], be[2 * kC], me[2 * kC], ie[2 * kC];
    int idx = blockIdx.x;
    int b = idx / (kH * kNC);
    int h = (idx / kNC) % kH;
    int n = idx % kNC;
    int prev = (n + kNC - 1) % kNC;
    size_t bhrow = (size_t)(b * kH + h) * kS;
    size_t kbase = bhrow * kDH;
    int tid = threadIdx.x;
    for (int t = tid; t < 2 * kC * kDH; t += 256) {
        int k = t >> 6, d = t & 63;
        int chunk = (k < kC) ? prev : n;
        int krow  = (k < kC) ? k : k - kC;
        ke[k][d] = skey[kbase + ((size_t)(chunk * kC + krow)) * kDH + d];
    }
    for (int t = tid; t < kC * kDH; t += 256) {
        int c = t >> 6, d = t & 63;
        qc[c][d] = sqk[kbase + ((size_t)(n * kC + c)) * kDH + d];
    }
    if (tid < kC) {
        bc[tid]  = sb[bhrow + n * kC + tid];
        icc[tid] = order[bhrow + n * kC + tid];
    }
    for (int t = tid; t < 2 * kC; t += 256) {
        int chunk = (t < kC) ? prev : n;
        int krow  = (t < kC) ? t : t - kC;
        be[t] = sb[bhrow + chunk * kC + krow];
        me[t] = sm[bhrow + chunk * kC + krow];
        ie[t] = order[bhrow + chunk * kC + krow];
    }
    __syncthreads();
    int wid = tid >> 6, lane = tid & 63;
    const float* vprev = sv + kbase + (size_t)prev * kC * kDH;
    const float* vcur  = sv + kbase + (size_t)n * kC * kDH;
    for (int it = 0; it < kC / 4; ++it) {
        int c = it * 4 + wid;
        int col0 = lane, col1 = kC + lane;
        float d0 = 0.f, d1 = 0.f;
#pragma unroll 8
        for (int d = 0; d < kDH; ++d) {
            float q = qc[c][d];
            d0 += q * ke[col0][d];
            d1 += q * ke[col1][d];
        }
        float v0 = d0 * 0.125f, v1 = d1 * 0.125f;   // / sqrt(64)
        int bcc = bc[c], icv = icc[c];
        if (bcc != be[col0] || me[col0] <= 0) v0 = -1e9f;
        if (bcc != be[col1] || me[col1] <= 0) v1 = -1e9f;
        if (icv == ie[col0]) v0 = -1e5f;            // self-mask last (overrides)
        if (icv == ie[col1]) v1 = -1e5f;
        float mx = fmaxf(v0, v1);
        for (int m = 32; m >= 1; m >>= 1) mx = fmaxf(mx, __shfl_xor(mx, m, 64));
        float e0 = expf(v0 - mx), e1 = expf(v1 - mx);
        float sum = e0 + e1;
        for (int m = 32; m >= 1; m >>= 1) sum += __shfl_xor(sum, m, 64);
        float p0 = e0 / sum, p1 = e1 / sum;
        float acc = 0.f;
        for (int k = 0; k < kC; ++k) {
            float a = __shfl(p0, k, 64);            // broadcast -> uniform branch
            if (a != 0.f) acc += a * vprev[(size_t)k * kDH + lane];
        }
        for (int k = 0; k < kC; ++k) {
            float a = __shfl(p1, k, 64);
            if (a != 0.f) acc += a * vcur[(size_t)k * kDH + lane];
        }
        aout[((size_t)(b * kS + icv)) * kD + h * kDH + lane] = acc;  // scatter = unsort
    }
}

// ============================================================
// host launcher
// ============================================================
extern "C" void kernel_launch(void* const* d_in, const int* in_sizes, int n_in,
                              void* d_out, int out_size, void* d_ws, size_t ws_size,
                              hipStream_t stream) {
    const int*   ids   = (const int*)d_in[0];
    const int*   amask = (const int*)d_in[1];
    const float* emb   = (const float*)d_in[2];
    const float* pos   = (const float*)d_in[3];
    const float* rot   = (const float*)d_in[4];
    const float* Wqk   = (const float*)d_in[5];
    const float* Wv    = (const float*)d_in[6];
    const float* Wo    = (const float*)d_in[7];
    const float* ln1g  = (const float*)d_in[8];
    const float* ln1b  = (const float*)d_in[9];
    const float* ln2g  = (const float*)d_in[10];
    const float* ln2b  = (const float*)d_in[11];
    const float* W1    = (const float*)d_in[12];
    const float* b1    = (const float*)d_in[13];
    const float* W2    = (const float*)d_in[14];
    const float* b2    = (const float*)d_in[15];
    const float* lnfg  = (const float*)d_in[16];
    const float* lnfb  = (const float*)d_in[17];
    const float* Wlm   = (const float*)d_in[18];
    const float* blm   = (const float*)d_in[19];
    float* out = (float*)d_out;

    const size_t NX  = (size_t)kB * kS * kD;    // 3,145,728 floats
    const size_t NBH = (size_t)kB * kH * kS;    // 49,152

    // Large fp32 scratch lives in d_out (256 MB; final GEMM rewrites all of it
    // and reads only xn/Wlm). Only xn + int arrays use d_ws (~13.4 MB).
    float* x     = out;            // [B,S,D]
    float* qk    = out + 1 * NX;   // [B,S,H*DH]
    float* v     = out + 2 * NX;
    float* sqk   = out + 3 * NX;   // sorted, [B,H,S,DH]
    float* skey  = out + 4 * NX;
    float* sv    = out + 5 * NX;
    float* aoutb = out + 6 * NX;   // attention output, unsorted [B,S,D]
    float* h1    = out + 7 * NX;   // FFN intermediate [B,S,F] = 4*NX
    float* xn    = (float*)d_ws;   // layernorm output [B,S,D]
    int* ibase   = (int*)((float*)d_ws + NX);
    int* buckets = ibase;
    int* order   = ibase + NBH;
    int* sb      = ibase + 2 * NBH;
    int* smv     = ibase + 3 * NBH;

    const int rows = kB * kS;  // 4096

    embed_kernel<<<rows, 256, 0, stream>>>(ids, emb, pos, x);

    for (int l = 0; l < kL; ++l) {
        ln_kernel<<<rows, 256, 0, stream>>>(x, ln1g + l * kD, ln1b + l * kD, xn);
        gemm_kernel<<<dim3(kD / 64, rows / 64), 256, 0, stream>>>(
            xn, Wqk + (size_t)l * kD * kD, nullptr, nullptr, qk, rows, kD, kD, 0);
        gemm_kernel<<<dim3(kD / 64, rows / 64), 256, 0, stream>>>(
            xn, Wv + (size_t)l * kD * kD, nullptr, nullptr, v, rows, kD, kD, 0);
        bucket_kernel<<<(kB * kH * kS) / 256, 256, 0, stream>>>(
            qk, rot + (size_t)l * kH * kDH * kNR, buckets);
        sort_kernel<<<kB * kH, 256, 0, stream>>>(buckets, order);
        gather_kernel<<<(kB * kH * kS) / 4, 256, 0, stream>>>(
            qk, v, buckets, amask, order, sqk, skey, sv, sb, smv);
        attn_kernel<<<kB * kH * kNC, 256, 0, stream>>>(
            sqk, skey, sv, sb, smv, order, aoutb);
        gemm_kernel<<<dim3(kD / 64, rows / 64), 256, 0, stream>>>(
            aoutb, Wo + (size_t)l * kD * kD, nullptr, x, x, rows, kD, kD, 0);
        ln_kernel<<<rows, 256, 0, stream>>>(x, ln2g + l * kD, ln2b + l * kD, xn);
        gemm_kernel<<<dim3(kF / 64, rows / 64), 256, 0, stream>>>(
            xn, W1 + (size_t)l * kD * kF, b1 + (size_t)l * kF, nullptr, h1, rows, kF, kD, 1);
        gemm_kernel<<<dim3(kD / 64, rows / 64), 256, 0, stream>>>(
            h1, W2 + (size_t)l * kF * kD, b2 + (size_t)l * kD, x, x, rows, kD, kF, 0);
    }

    ln_kernel<<<rows, 256, 0, stream>>>(x, lnfg, lnfb, xn);
    gemm_kernel<<<dim3(kV / 64, rows / 64), 256, 0, stream>>>(
        xn, Wlm, blm, nullptr, out, rows, kV, kD, 0);
}